// Round 14
// baseline (747.983 us; speedup 1.0000x reference)
//
#include <hip/hip_runtime.h>
#include <math.h>

#define NN 50000
#define EE 800000
#define IN_F 30
#define NH 8
#define DH 32
#define HD 256      // NH*DH
#define NG 512
#define NHID 128
#define ALPHA 0.2f

#define SCAN_B 256
#define SCAN_NB ((NN + SCAN_B - 1)/SCAN_B)   // 196
#define DB 64                                 // degree buckets

typedef unsigned short u16;
typedef __attribute__((ext_vector_type(8))) short bf16x8;
typedef __attribute__((ext_vector_type(4))) float f32x4;

// ---------- bf16 helpers (round-to-nearest-even) ----------
__device__ __forceinline__ u16 f2bf(float f){
  unsigned u = __float_as_uint(f);
  u = u + 0x7FFFu + ((u >> 16) & 1u);
  return (u16)(u >> 16);
}
__device__ __forceinline__ float bf2f(u16 b){
  return __uint_as_float(((unsigned)b) << 16);
}
__device__ __forceinline__ float4 bf4_to_f4(ushort4 v){
  float4 r; r.x=bf2f(v.x); r.y=bf2f(v.y); r.z=bf2f(v.z); r.w=bf2f(v.w); return r;
}

// ---------- init: zero counts + graph counts ----------
__global__ void k_init(int* counts, int* gcounts){
  int i = blockIdx.x*blockDim.x + threadIdx.x;
  if(i < NN) counts[i] = 0;
  if(i < NG) gcounts[i] = 0;
}

// ---------- CSR build: histogram by dst ----------
__global__ void k_hist(const int* __restrict__ dst, int* counts){
  int i = blockIdx.x*blockDim.x + threadIdx.x;
  if(i < EE) atomicAdd(&counts[dst[i]], 1);
}

// ---------- graph histogram (gid sorted -> contiguous segments) ----------
__global__ void k_ghist(const int* __restrict__ gid, int* gcounts){
  int i = blockIdx.x*blockDim.x + threadIdx.x;
  if(i < NN) atomicAdd(&gcounts[gid[i]], 1);
}

// ---------- exclusive scan of the 512 graph counts (one block) ----------
__global__ void k_gscan(const int* __restrict__ gcounts, int* __restrict__ gstart){
  __shared__ int sd[NG];
  int t = threadIdx.x;
  int v = gcounts[t];
  sd[t]=v; __syncthreads();
  for(int off=1; off<NG; off<<=1){
    int u = (t>=off)? sd[t-off] : 0;
    __syncthreads();
    sd[t] += u;
    __syncthreads();
  }
  gstart[t] = sd[t]-v;     // exclusive
}

// ---------- hierarchical exclusive scan: phase 1 (block sums) ----------
__global__ void k_scan_partial(const int* __restrict__ counts, int* __restrict__ bsums){
  __shared__ int sd[SCAN_B];
  int b = blockIdx.x, t = threadIdx.x;
  int idx = b*SCAN_B + t;
  sd[t] = (idx<NN)? counts[idx] : 0;
  __syncthreads();
  for(int off=SCAN_B/2; off>0; off>>=1){
    if(t<off) sd[t] += sd[t+off];
    __syncthreads();
  }
  if(t==0) bsums[b] = sd[0];
}

// ---------- phase 2: exclusive scan of the 196 block sums ----------
__global__ void k_scan_bsums(int* bsums){
  __shared__ int sd[SCAN_B];
  int t = threadIdx.x;
  int v = (t<SCAN_NB)? bsums[t] : 0;
  sd[t]=v; __syncthreads();
  for(int off=1; off<SCAN_B; off<<=1){
    int u = (t>=off)? sd[t-off] : 0;
    __syncthreads();
    sd[t] += u;
    __syncthreads();
  }
  if(t<SCAN_NB) bsums[t] = sd[t]-v;     // exclusive
}

// ---------- phase 3: block-local scan + offset -> start, cursor ----------
__global__ void k_scan_final(const int* __restrict__ counts, const int* __restrict__ bsums,
                             int* __restrict__ start, int* __restrict__ cursor){
  __shared__ int sd[SCAN_B];
  int b = blockIdx.x, t = threadIdx.x;
  int idx = b*SCAN_B + t;
  int v = (idx<NN)? counts[idx] : 0;
  sd[t]=v; __syncthreads();
  for(int off=1; off<SCAN_B; off<<=1){
    int u = (t>=off)? sd[t-off] : 0;
    __syncthreads();
    sd[t] += u;
    __syncthreads();
  }
  int ex = sd[t]-v + bsums[b];
  if(idx<NN){ start[idx]=ex; cursor[idx]=ex; }
}

// ---------- scatter SOURCE NODE IDS into dst-grouped order ----------
__global__ void k_scatter(const int* __restrict__ dst, const int* __restrict__ src,
                          int* cursor, int* __restrict__ csr_src){
  int i = blockIdx.x*blockDim.x + threadIdx.x;
  if(i<EE){ int p = atomicAdd(&cursor[dst[i]],1); csr_src[p]=src[i]; }
}

// ---------- degree sort, contention-free ----------
// Phase A: per-block LDS histogram -> dloc[b*DB+bin] (no global atomics).
__global__ void k_dloc(const int* __restrict__ counts, int* __restrict__ dloc){
  __shared__ int hloc[DB];
  int b = blockIdx.x, t = threadIdx.x;
  if(t < DB) hloc[t] = 0;
  __syncthreads();
  int idx = b*SCAN_B + t;
  if(idx < NN){ int bin = min(counts[idx], DB-1); atomicAdd(&hloc[bin], 1); }
  __syncthreads();
  if(t < DB) dloc[b*DB + t] = hloc[t];
}
// Phase B: one block, DB threads; column scan over blocks + bin-offset scan.
__global__ void k_dbase(const int* __restrict__ dloc, int* __restrict__ dbase){
  __shared__ int tot[DB];
  int t = threadIdx.x;       // bin
  int run = 0;
  for(int b=0;b<SCAN_NB;b++){ int v = dloc[b*DB+t]; dbase[b*DB+t] = run; run += v; }
  tot[t] = run;
  __syncthreads();
  // exclusive scan of totals
  int v = tot[t];
  __syncthreads();
  int off_acc = 0;
  for(int off=1; off<DB; off<<=1){
    int u = (t>=off)? tot[t-off] : 0;
    __syncthreads();
    tot[t] += u;
    __syncthreads();
  }
  off_acc = tot[t] - v;      // exclusive bin offset
  for(int b=0;b<SCAN_NB;b++) dbase[b*DB+t] += off_acc;
}
// Phase C: scatter with per-block LDS cursors (LDS atomics only).
__global__ void k_dscatter(const int* __restrict__ counts, const int* __restrict__ dbase,
                           int* __restrict__ node_order){
  __shared__ int cur[DB];
  int b = blockIdx.x, t = threadIdx.x;
  if(t < DB) cur[t] = dbase[b*DB + t];
  __syncthreads();
  int idx = b*SCAN_B + t;
  if(idx < NN){
    int bin = min(counts[idx], DB-1);
    int p = atomicAdd(&cur[bin], 1);
    node_order[p] = idx;
  }
}

// ---------- W2 transpose + bf16 convert: W2T[n*HD+k] = bf16(W2[k*HD+n]) ----------
__global__ void k_w2t(const float* __restrict__ W2, u16* __restrict__ W2T){
  int i = blockIdx.x*blockDim.x + threadIdx.x;
  if(i >= HD*HD) return;
  int n = i >> 8, k = i & 255;
  W2T[i] = f2bf(W2[k*HD + n]);
}

// ---------- layer-1 projection + FUSED elr: feat16 = bf16(x @ W1); el/er ----------
#define TM1 16
__global__ void k_proj1(const float* __restrict__ x, const float* __restrict__ W1,
                        const float* __restrict__ al1, const float* __restrict__ ar1,
                        u16* __restrict__ feat16, float* __restrict__ el,
                        float* __restrict__ er){
  __shared__ float xs[TM1][IN_F];
  int n0 = blockIdx.x*TM1;
  int t = threadIdx.x;
  for(int i=t;i<TM1*IN_F;i+=256){
    int m=i/IN_F, k=i-m*IN_F;
    xs[m][k] = x[(size_t)(n0+m)*IN_F+k];
  }
  __syncthreads();
  int l = t & 63;
  int jq = l << 2;                           // col 0..252 step 4
  int m0 = t >> 6;                           // wave id 0..3
  float4 acc[4];
  #pragma unroll
  for(int r=0;r<4;r++){ acc[r].x=0.f; acc[r].y=0.f; acc[r].z=0.f; acc[r].w=0.f; }
  for(int k=0;k<IN_F;k++){
    float4 w = *(const float4*)&W1[k*HD + jq];
    #pragma unroll
    for(int r=0;r<4;r++){
      float xv = xs[m0 + (r<<2)][k];
      acc[r].x += xv*w.x; acc[r].y += xv*w.y; acc[r].z += xv*w.z; acc[r].w += xv*w.w;
    }
  }
  // fused attention logits: head h = l>>3; al1/ar1 index == jq
  float4 av = *(const float4*)&al1[jq];
  float4 bv = *(const float4*)&ar1[jq];
  int h = l >> 3;
  #pragma unroll
  for(int r=0;r<4;r++){
    int n = n0 + m0 + (r<<2);
    ushort4 o; o.x=f2bf(acc[r].x); o.y=f2bf(acc[r].y); o.z=f2bf(acc[r].z); o.w=f2bf(acc[r].w);
    *(ushort4*)&feat16[(size_t)n*HD + jq] = o;
    float pe = acc[r].x*av.x + acc[r].y*av.y + acc[r].z*av.z + acc[r].w*av.w;
    float pr = acc[r].x*bv.x + acc[r].y*bv.y + acc[r].z*bv.z + acc[r].w*bv.w;
    pe += __shfl_xor(pe,1,64); pe += __shfl_xor(pe,2,64); pe += __shfl_xor(pe,4,64);
    pr += __shfl_xor(pr,1,64); pr += __shfl_xor(pr,2,64); pr += __shfl_xor(pr,4,64);
    if((l&7)==0){ el[n*NH+h]=pe; er[n*NH+h]=pr; }
  }
}

// ---------- layer-2 projection via MFMA: feat2 = bf16(h1b @ W2) ----------
__global__ void k_proj2m(const u16* __restrict__ h1b, const u16* __restrict__ W2T,
                         u16* __restrict__ Y16){
  int t = threadIdx.x;
  int wave = t>>6, lane = t&63;
  int m0 = blockIdx.x*64 + wave*16;
  int c0 = blockIdx.y*64;
  int lm = lane & 15, lq = lane >> 4;
  int arow = m0 + lm; if(arow >= NN) arow = NN-1;   // clamp (stores guarded)
  const u16* Aptr = h1b + (size_t)arow*HD + lq*8;
  f32x4 acc[4];
  #pragma unroll
  for(int ct=0;ct<4;ct++) acc[ct] = (f32x4){0.f,0.f,0.f,0.f};
  #pragma unroll
  for(int k0=0;k0<HD;k0+=32){
    bf16x8 a = *(const bf16x8*)(Aptr + k0);
    #pragma unroll
    for(int ct=0;ct<4;ct++){
      bf16x8 b = *(const bf16x8*)(W2T + (size_t)(c0 + ct*16 + lm)*HD + k0 + lq*8);
      acc[ct] = __builtin_amdgcn_mfma_f32_16x16x32_bf16(a, b, acc[ct], 0, 0, 0);
    }
  }
  int orow0 = m0 + lq*4;
  #pragma unroll
  for(int ct=0;ct<4;ct++){
    #pragma unroll
    for(int r=0;r<4;r++){
      int n = orow0 + r;
      if(n < NN) Y16[(size_t)n*HD + c0 + ct*16 + lm] = f2bf(acc[ct][r]);
    }
  }
}

// ---------- attention logits el/er (layer 2) from bf16 feat ----------
__global__ void k_elr(const u16* __restrict__ feat16, const float* __restrict__ al,
                      const float* __restrict__ ar, float* __restrict__ el,
                      float* __restrict__ er){
  int i = blockIdx.x*blockDim.x + threadIdx.x;  // n*8+h
  if(i >= NN*NH) return;
  int h = i & 7;
  const ushort4* f4 = (const ushort4*)(feat16 + (size_t)i*DH);
  const float4* a4 = (const float4*)(al + h*DH);
  const float4* b4 = (const float4*)(ar + h*DH);
  float ea=0.f, eb=0.f;
  #pragma unroll
  for(int q=0;q<8;q++){
    float4 f=bf4_to_f4(f4[q]); float4 a=a4[q], b=b4[q];
    ea += f.x*a.x + f.y*a.y + f.z*a.z + f.w*a.w;
    eb += f.x*b.x + f.y*b.y + f.z*b.z + f.w*b.w;
  }
  el[i]=ea; er[i]=eb;
}

// ---------- per-node softmax aggregation: 2 edges/iteration, 16B/lane ----------
__device__ __forceinline__ void gat_agg2(int n, int lane,
    const u16* __restrict__ feat16, const float* __restrict__ el,
    const float* __restrict__ er, const int* __restrict__ start,
    const int* __restrict__ counts, const int* __restrict__ csr_src,
    float* A){
  int half = lane >> 5;
  int l = lane & 31;
  int h = l >> 2;
  int col8 = l << 3;
  float erh = er[n*NH + h];
  int st = start[n], cnt = counts[n];
  float s = 0.f;
  #pragma unroll
  for(int j=0;j<8;j++) A[j]=0.f;
  for(int c=0; c<cnt; c+=64){
    int nrem = cnt - c;
    int lim = nrem < 64 ? nrem : 64;
    int myIdx = csr_src[st + c + (lane < lim ? lane : lim-1)];
    #pragma unroll 4
    for(int k=0; k<lim; k+=2){
      int sel = k + half;
      int sidx = __shfl(myIdx, sel, 64);
      float e = el[(size_t)sidx*NH + h] + erh;
      e = (e>0.f)? e : ALPHA*e;
      float w = (sel < lim) ? __expf(e) : 0.f;
      uint4 rv = *(const uint4*)&feat16[(size_t)sidx*HD + col8];
      float f0 = __uint_as_float(rv.x << 16);
      float f1 = __uint_as_float(rv.x & 0xffff0000u);
      float f2 = __uint_as_float(rv.y << 16);
      float f3 = __uint_as_float(rv.y & 0xffff0000u);
      float f4 = __uint_as_float(rv.z << 16);
      float f5 = __uint_as_float(rv.z & 0xffff0000u);
      float f6 = __uint_as_float(rv.w << 16);
      float f7 = __uint_as_float(rv.w & 0xffff0000u);
      s += w;
      A[0]+=w*f0; A[1]+=w*f1; A[2]+=w*f2; A[3]+=w*f3;
      A[4]+=w*f4; A[5]+=w*f5; A[6]+=w*f6; A[7]+=w*f7;
    }
  }
  s += __shfl_xor(s, 32, 64);
  #pragma unroll
  for(int j=0;j<8;j++) A[j] += __shfl_xor(A[j], 32, 64);
  float inv = 1.f/fmaxf(s, 1e-9f);
  #pragma unroll
  for(int j=0;j<8;j++) A[j] *= inv;
}

// ---------- layer 1 finalize: + b1 + x@resW1, ELU -> h1b (bf16) ----------
__global__ void k_gat1(const u16* __restrict__ feat16, const float* __restrict__ el,
    const float* __restrict__ er, const int* __restrict__ start,
    const int* __restrict__ counts, const int* __restrict__ csr_src,
    const int* __restrict__ node_order, const float* __restrict__ x,
    const float* __restrict__ resW1, const float* __restrict__ b1,
    u16* __restrict__ h1b){
  int n = node_order[blockIdx.x*4 + (threadIdx.x>>6)];
  int lane = threadIdx.x & 63;
  float A[8];
  gat_agg2(n,lane,feat16,el,er,start,counts,csr_src,A);
  int half = lane>>5, l = lane&31;
  int col8 = l<<3;
  float r[8];
  #pragma unroll
  for(int j=0;j<8;j++) r[j]=0.f;
  const float* xrow = x + (size_t)n*IN_F;
  int kb = half*15;
  #pragma unroll
  for(int k=0;k<15;k++){
    float xv = xrow[kb+k];
    const float4 w0 = *(const float4*)&resW1[(kb+k)*HD + col8];
    const float4 w1 = *(const float4*)&resW1[(kb+k)*HD + col8 + 4];
    r[0]+=xv*w0.x; r[1]+=xv*w0.y; r[2]+=xv*w0.z; r[3]+=xv*w0.w;
    r[4]+=xv*w1.x; r[5]+=xv*w1.y; r[6]+=xv*w1.z; r[7]+=xv*w1.w;
  }
  #pragma unroll
  for(int j=0;j<8;j++) r[j] += __shfl_xor(r[j], 32, 64);
  if(half==0){
    const float4 b0 = *(const float4*)&b1[col8];
    const float4 b4 = *(const float4*)&b1[col8+4];
    float v; ushort4 q0, q1;
    v = A[0]+r[0]+b0.x; q0.x = f2bf((v>0.f)? v : expf(v)-1.f);
    v = A[1]+r[1]+b0.y; q0.y = f2bf((v>0.f)? v : expf(v)-1.f);
    v = A[2]+r[2]+b0.z; q0.z = f2bf((v>0.f)? v : expf(v)-1.f);
    v = A[3]+r[3]+b0.w; q0.w = f2bf((v>0.f)? v : expf(v)-1.f);
    v = A[4]+r[4]+b4.x; q1.x = f2bf((v>0.f)? v : expf(v)-1.f);
    v = A[5]+r[5]+b4.y; q1.y = f2bf((v>0.f)? v : expf(v)-1.f);
    v = A[6]+r[6]+b4.z; q1.z = f2bf((v>0.f)? v : expf(v)-1.f);
    v = A[7]+r[7]+b4.w; q1.w = f2bf((v>0.f)? v : expf(v)-1.f);
    *(ushort4*)&h1b[(size_t)n*HD + col8]     = q0;
    *(ushort4*)&h1b[(size_t)n*HD + col8 + 4] = q1;
  }
}

// ---------- layer 2 finalize: + b2 + h1b residual, mean over heads -> h2 ----------
__global__ void k_gat2(const u16* __restrict__ feat16, const float* __restrict__ el,
    const float* __restrict__ er, const int* __restrict__ start,
    const int* __restrict__ counts, const int* __restrict__ csr_src,
    const int* __restrict__ node_order, const u16* __restrict__ h1b,
    const float* __restrict__ b2, float* __restrict__ h2){
  int n = node_order[blockIdx.x*4 + (threadIdx.x>>6)];
  int lane = threadIdx.x & 63;
  float A[8];
  gat_agg2(n,lane,feat16,el,er,start,counts,csr_src,A);
  int l = lane&31;
  int col8 = l<<3;
  if(lane<32){
    const float4 b0 = *(const float4*)&b2[col8];
    const float4 b4 = *(const float4*)&b2[col8+4];
    float4 h0 = bf4_to_f4(*(const ushort4*)&h1b[(size_t)n*HD + col8]);
    float4 h4 = bf4_to_f4(*(const ushort4*)&h1b[(size_t)n*HD + col8 + 4]);
    float t[8];
    t[0]=A[0]+b0.x+h0.x; t[1]=A[1]+b0.y+h0.y; t[2]=A[2]+b0.z+h0.z; t[3]=A[3]+b0.w+h0.w;
    t[4]=A[4]+b4.x+h4.x; t[5]=A[5]+b4.y+h4.y; t[6]=A[6]+b4.z+h4.z; t[7]=A[7]+b4.w+h4.w;
    // head-sum: lane l = h*4+p; reduce over h bits (offsets 4,8,16)
    #pragma unroll
    for(int off=4; off<32; off<<=1){
      #pragma unroll
      for(int j=0;j<8;j++) t[j] += __shfl_xor(t[j], off, 64);
    }
    if(l<4){
      float4 o0, o1;
      o0.x=t[0]*0.125f; o0.y=t[1]*0.125f; o0.z=t[2]*0.125f; o0.w=t[3]*0.125f;
      o1.x=t[4]*0.125f; o1.y=t[5]*0.125f; o1.z=t[6]*0.125f; o1.w=t[7]*0.125f;
      *(float4*)&h2[(size_t)n*DH + (l<<3)]     = o0;
      *(float4*)&h2[(size_t)n*DH + (l<<3) + 4] = o1;
    }
  }
}

// ---------- segmented readout + fused gate (NO atomics; gid is sorted) ----------
__global__ void k_readout(const float* __restrict__ h2, const float* __restrict__ Ww,
    const float* __restrict__ bw, const int* __restrict__ gstart,
    const int* __restrict__ gcounts, float* __restrict__ gsum,
    float* __restrict__ gmaxf){
  __shared__ float ssum[8][DH];
  __shared__ float smax[8][DH];
  int g = blockIdx.x;
  int t = threadIdx.x;
  int half = (t & 63) >> 5;
  int wid = t >> 6;
  int l = t & 31;
  int rg = wid*2 + half;               // row group 0..7
  int s = gstart[g], cnt = gcounts[g];
  float w_d = Ww[l];
  float bw0 = bw[0];
  float sum = 0.f, mx = -INFINITY;
  for(int r = rg; r < cnt; r += 8){
    float v = h2[(size_t)(s+r)*DH + l];
    float p = v*w_d;
    p += __shfl_xor(p,1,64); p += __shfl_xor(p,2,64); p += __shfl_xor(p,4,64);
    p += __shfl_xor(p,8,64); p += __shfl_xor(p,16,64);
    float wg = 1.f/(1.f+__expf(-(p+bw0)));
    sum += wg*v;
    mx = fmaxf(mx, v);
  }
  ssum[rg][l] = sum;
  smax[rg][l] = mx;
  __syncthreads();
  if(t < DH){
    float a = 0.f, m = -INFINITY;
    #pragma unroll
    for(int r=0;r<8;r++){ a += ssum[r][t]; m = fmaxf(m, smax[r][t]); }
    gsum[g*DH+t]  = a;
    gmaxf[g*DH+t] = isfinite(m)? m : 0.f;
  }
}

// ---------- MLP predictor: one block (128 thr) per graph ----------
__global__ void k_mlp(const float* __restrict__ gsum, const float* __restrict__ gmaxf,
    const float* __restrict__ Wp1, const float* __restrict__ bp1,
    const float* __restrict__ gamma, const float* __restrict__ beta,
    const float* __restrict__ rm, const float* __restrict__ rv,
    const float* __restrict__ Wp2, const float* __restrict__ bp2,
    float* __restrict__ out){
  __shared__ float gs[2*DH];
  __shared__ float red[NHID];
  int g = blockIdx.x, t = threadIdx.x;
  if(t < DH) gs[t] = gsum[g*DH + t];
  else if(t < 2*DH) gs[t] = gmaxf[g*DH + (t-DH)];
  __syncthreads();
  float acc = bp1[t];
  #pragma unroll
  for(int k=0;k<2*DH;k++) acc += gs[k]*Wp1[k*NHID + t];
  acc = fmaxf(acc, 0.f);
  acc = (acc - rm[t])*rsqrtf(rv[t]+1e-5f)*gamma[t] + beta[t];
  red[t] = acc*Wp2[t];
  __syncthreads();
  for(int off=NHID/2; off>0; off>>=1){
    if(t<off) red[t] += red[t+off];
    __syncthreads();
  }
  if(t==0) out[g] = red[0] + bp2[0];
}

extern "C" void kernel_launch(void* const* d_in, const int* in_sizes, int n_in,
                              void* d_out, int out_size, void* d_ws, size_t ws_size,
                              hipStream_t stream){
  const float* x    = (const float*)d_in[0];
  const int*   src  = (const int*)  d_in[1];
  const int*   dst  = (const int*)  d_in[2];
  const int*   gid  = (const int*)  d_in[3];
  const float* W1   = (const float*)d_in[4];
  const float* al1  = (const float*)d_in[5];
  const float* ar1  = (const float*)d_in[6];
  const float* b1   = (const float*)d_in[7];
  const float* resW1= (const float*)d_in[8];
  const float* W2   = (const float*)d_in[9];
  const float* al2  = (const float*)d_in[10];
  const float* ar2  = (const float*)d_in[11];
  const float* b2   = (const float*)d_in[12];
  const float* Ww   = (const float*)d_in[13];
  const float* bw   = (const float*)d_in[14];
  const float* Wp1  = (const float*)d_in[15];
  const float* bp1  = (const float*)d_in[16];
  const float* gamma= (const float*)d_in[17];
  const float* beta = (const float*)d_in[18];
  const float* rm   = (const float*)d_in[19];
  const float* rv   = (const float*)d_in[20];
  const float* Wp2  = (const float*)d_in[21];
  const float* bp2  = (const float*)d_in[22];
  float* out = (float*)d_out;

  char* w = (char*)d_ws;
  u16*      feat16 = (u16*)w;      w += (size_t)NN*HD*2;
  u16*      h1b    = (u16*)w;      w += (size_t)NN*HD*2;
  u16*      W2T    = (u16*)w;      w += (size_t)HD*HD*2;
  float*    el     = (float*)w;    w += (size_t)NN*NH*4;
  float*    er     = (float*)w;    w += (size_t)NN*NH*4;
  float*    h2     = (float*)w;    w += (size_t)NN*DH*4;
  float*    gsum   = (float*)w;    w += (size_t)NG*DH*4;
  float*    gmaxf  = (float*)w;    w += (size_t)NG*DH*4;
  int*      counts = (int*)w;      w += (size_t)NN*4;
  int*      start  = (int*)w;      w += (size_t)NN*4;
  int*      cursor = (int*)w;      w += (size_t)NN*4;
  int*      bsums  = (int*)w;      w += (size_t)SCAN_NB*4;
  int*      gcounts= (int*)w;      w += (size_t)NG*4;
  int*      gstart = (int*)w;      w += (size_t)NG*4;
  int*      dloc   = (int*)w;      w += (size_t)SCAN_NB*DB*4;
  int*      dbase  = (int*)w;      w += (size_t)SCAN_NB*DB*4;
  int*      node_order=(int*)w;    w += (size_t)NN*4;
  int*      csr_src= (int*)w;      w += (size_t)EE*4;

  hipLaunchKernelGGL(k_init,         dim3((NN+255)/256),       dim3(256),    0, stream, counts, gcounts);
  hipLaunchKernelGGL(k_hist,         dim3((EE+255)/256),       dim3(256),    0, stream, dst, counts);
  hipLaunchKernelGGL(k_ghist,        dim3((NN+255)/256),       dim3(256),    0, stream, gid, gcounts);
  hipLaunchKernelGGL(k_gscan,        dim3(1),                  dim3(NG),     0, stream, gcounts, gstart);
  hipLaunchKernelGGL(k_scan_partial, dim3(SCAN_NB),            dim3(SCAN_B), 0, stream, counts, bsums);
  hipLaunchKernelGGL(k_scan_bsums,   dim3(1),                  dim3(SCAN_B), 0, stream, bsums);
  hipLaunchKernelGGL(k_scan_final,   dim3(SCAN_NB),            dim3(SCAN_B), 0, stream, counts, bsums, start, cursor);
  hipLaunchKernelGGL(k_scatter,      dim3((EE+255)/256),       dim3(256),    0, stream, dst, src, cursor, csr_src);
  hipLaunchKernelGGL(k_dloc,         dim3(SCAN_NB),            dim3(SCAN_B), 0, stream, counts, dloc);
  hipLaunchKernelGGL(k_dbase,        dim3(1),                  dim3(DB),     0, stream, dloc, dbase);
  hipLaunchKernelGGL(k_dscatter,     dim3(SCAN_NB),            dim3(SCAN_B), 0, stream, counts, dbase, node_order);
  hipLaunchKernelGGL(k_w2t,          dim3((HD*HD+255)/256),    dim3(256),    0, stream, W2, W2T);
  hipLaunchKernelGGL(k_proj1,        dim3(NN/TM1),             dim3(256),    0, stream, x, W1, al1, ar1, feat16, el, er);
  hipLaunchKernelGGL(k_gat1,         dim3(NN/4),               dim3(256),    0, stream, feat16, el, er, start, counts, csr_src, node_order, x, resW1, b1, h1b);
  hipLaunchKernelGGL(k_proj2m,       dim3((NN+63)/64, HD/64),  dim3(256),    0, stream, h1b, W2T, feat16);
  hipLaunchKernelGGL(k_elr,          dim3((NN*NH+255)/256),    dim3(256),    0, stream, feat16, al2, ar2, el, er);
  hipLaunchKernelGGL(k_gat2,         dim3(NN/4),               dim3(256),    0, stream, feat16, el, er, start, counts, csr_src, node_order, h1b, b2, h2);
  hipLaunchKernelGGL(k_readout,      dim3(NG),                 dim3(256),    0, stream, h2, Ww, bw, gstart, gcounts, gsum, gmaxf);
  hipLaunchKernelGGL(k_mlp,          dim3(NG),                 dim3(NHID),   0, stream, gsum, gmaxf, Wp1, bp1, gamma, beta, rm, rv, Wp2, bp2, out);
}

// Round 15
// 530.867 us; speedup vs baseline: 1.4090x; 1.4090x over previous
//
#include <hip/hip_runtime.h>
#include <math.h>

#define NN 50000
#define EE 800000
#define IN_F 30
#define NH 8
#define DH 32
#define HD 256      // NH*DH
#define NG 512
#define NHID 128
#define ALPHA 0.2f

#define SCAN_B 256
#define SCAN_NB ((NN + SCAN_B - 1)/SCAN_B)   // 196

typedef unsigned short u16;
typedef __attribute__((ext_vector_type(8))) short bf16x8;
typedef __attribute__((ext_vector_type(4))) float f32x4;

// ---------- bf16 helpers (round-to-nearest-even) ----------
__device__ __forceinline__ u16 f2bf(float f){
  unsigned u = __float_as_uint(f);
  u = u + 0x7FFFu + ((u >> 16) & 1u);
  return (u16)(u >> 16);
}
__device__ __forceinline__ float bf2f(u16 b){
  return __uint_as_float(((unsigned)b) << 16);
}
__device__ __forceinline__ float4 bf4_to_f4(ushort4 v){
  float4 r; r.x=bf2f(v.x); r.y=bf2f(v.y); r.z=bf2f(v.z); r.w=bf2f(v.w); return r;
}

// ---------- init: zero counts + graph counts ----------
__global__ void k_init(int* counts, int* gcounts){
  int i = blockIdx.x*blockDim.x + threadIdx.x;
  if(i < NN) counts[i] = 0;
  if(i < NG) gcounts[i] = 0;
}

// ---------- CSR build: histogram by dst ----------
__global__ void k_hist(const int* __restrict__ dst, int* counts){
  int i = blockIdx.x*blockDim.x + threadIdx.x;
  if(i < EE) atomicAdd(&counts[dst[i]], 1);
}

// ---------- graph histogram (gid sorted -> contiguous segments) ----------
__global__ void k_ghist(const int* __restrict__ gid, int* gcounts){
  int i = blockIdx.x*blockDim.x + threadIdx.x;
  if(i < NN) atomicAdd(&gcounts[gid[i]], 1);
}

// ---------- exclusive scan of the 512 graph counts (one block) ----------
__global__ void k_gscan(const int* __restrict__ gcounts, int* __restrict__ gstart){
  __shared__ int sd[NG];
  int t = threadIdx.x;
  int v = gcounts[t];
  sd[t]=v; __syncthreads();
  for(int off=1; off<NG; off<<=1){
    int u = (t>=off)? sd[t-off] : 0;
    __syncthreads();
    sd[t] += u;
    __syncthreads();
  }
  gstart[t] = sd[t]-v;     // exclusive
}

// ---------- hierarchical exclusive scan: phase 1 (block sums) ----------
__global__ void k_scan_partial(const int* __restrict__ counts, int* __restrict__ bsums){
  __shared__ int sd[SCAN_B];
  int b = blockIdx.x, t = threadIdx.x;
  int idx = b*SCAN_B + t;
  sd[t] = (idx<NN)? counts[idx] : 0;
  __syncthreads();
  for(int off=SCAN_B/2; off>0; off>>=1){
    if(t<off) sd[t] += sd[t+off];
    __syncthreads();
  }
  if(t==0) bsums[b] = sd[0];
}

// ---------- phase 2: exclusive scan of the 196 block sums ----------
__global__ void k_scan_bsums(int* bsums){
  __shared__ int sd[SCAN_B];
  int t = threadIdx.x;
  int v = (t<SCAN_NB)? bsums[t] : 0;
  sd[t]=v; __syncthreads();
  for(int off=1; off<SCAN_B; off<<=1){
    int u = (t>=off)? sd[t-off] : 0;
    __syncthreads();
    sd[t] += u;
    __syncthreads();
  }
  if(t<SCAN_NB) bsums[t] = sd[t]-v;     // exclusive
}

// ---------- phase 3: block-local scan + offset -> start, cursor ----------
__global__ void k_scan_final(const int* __restrict__ counts, const int* __restrict__ bsums,
                             int* __restrict__ start, int* __restrict__ cursor){
  __shared__ int sd[SCAN_B];
  int b = blockIdx.x, t = threadIdx.x;
  int idx = b*SCAN_B + t;
  int v = (idx<NN)? counts[idx] : 0;
  sd[t]=v; __syncthreads();
  for(int off=1; off<SCAN_B; off<<=1){
    int u = (t>=off)? sd[t-off] : 0;
    __syncthreads();
    sd[t] += u;
    __syncthreads();
  }
  int ex = sd[t]-v + bsums[b];
  if(idx<NN){ start[idx]=ex; cursor[idx]=ex; }
}

// ---------- scatter SOURCE NODE IDS into dst-grouped order ----------
__global__ void k_scatter(const int* __restrict__ dst, const int* __restrict__ src,
                          int* cursor, int* __restrict__ csr_src){
  int i = blockIdx.x*blockDim.x + threadIdx.x;
  if(i<EE){ int p = atomicAdd(&cursor[dst[i]],1); csr_src[p]=src[i]; }
}

// ---------- W2 transpose + bf16 convert: W2T[n*HD+k] = bf16(W2[k*HD+n]) ----------
__global__ void k_w2t(const float* __restrict__ W2, u16* __restrict__ W2T){
  int i = blockIdx.x*blockDim.x + threadIdx.x;
  if(i >= HD*HD) return;
  int n = i >> 8, k = i & 255;
  W2T[i] = f2bf(W2[k*HD + n]);
}

// ---------- layer-1 projection: feat16 = bf16(x(N,30) @ W1(30,256)) ----------
#define TM1 16
__global__ void k_proj1(const float* __restrict__ x, const float* __restrict__ W1,
                        u16* __restrict__ feat16){
  __shared__ float xs[TM1][IN_F];
  int n0 = blockIdx.x*TM1;
  int t = threadIdx.x;
  for(int i=t;i<TM1*IN_F;i+=256){
    int m=i/IN_F, k=i-m*IN_F;
    xs[m][k] = x[(size_t)(n0+m)*IN_F+k];
  }
  __syncthreads();
  int jq = (t & 63) << 2;
  int m0 = t >> 6;
  float4 acc[4];
  #pragma unroll
  for(int r=0;r<4;r++){ acc[r].x=0.f; acc[r].y=0.f; acc[r].z=0.f; acc[r].w=0.f; }
  for(int k=0;k<IN_F;k++){
    float4 w = *(const float4*)&W1[k*HD + jq];
    #pragma unroll
    for(int r=0;r<4;r++){
      float xv = xs[m0 + (r<<2)][k];
      acc[r].x += xv*w.x; acc[r].y += xv*w.y; acc[r].z += xv*w.z; acc[r].w += xv*w.w;
    }
  }
  #pragma unroll
  for(int r=0;r<4;r++){
    int n = n0 + m0 + (r<<2);
    ushort4 o; o.x=f2bf(acc[r].x); o.y=f2bf(acc[r].y); o.z=f2bf(acc[r].z); o.w=f2bf(acc[r].w);
    *(ushort4*)&feat16[(size_t)n*HD + jq] = o;
  }
}

// ---------- layer-2 projection via MFMA: feat2 = bf16(h1b @ W2) ----------
// Block: 4 waves; wave w owns rows m0..m0+15, 64 cols of this col-block.
// A frag: A[m=lane&15][k=quad*8+j]; B frag from W2T: B[n=lane&15][k];
// C/D: col=lane&15, row=quad*4+reg (verified layouts).
__global__ void k_proj2m(const u16* __restrict__ h1b, const u16* __restrict__ W2T,
                         u16* __restrict__ Y16){
  int t = threadIdx.x;
  int wave = t>>6, lane = t&63;
  int m0 = blockIdx.x*64 + wave*16;
  int c0 = blockIdx.y*64;
  int lm = lane & 15, lq = lane >> 4;
  int arow = m0 + lm; if(arow >= NN) arow = NN-1;   // clamp (stores guarded)
  const u16* Aptr = h1b + (size_t)arow*HD + lq*8;
  f32x4 acc[4];
  #pragma unroll
  for(int ct=0;ct<4;ct++) acc[ct] = (f32x4){0.f,0.f,0.f,0.f};
  #pragma unroll
  for(int k0=0;k0<HD;k0+=32){
    bf16x8 a = *(const bf16x8*)(Aptr + k0);
    #pragma unroll
    for(int ct=0;ct<4;ct++){
      bf16x8 b = *(const bf16x8*)(W2T + (size_t)(c0 + ct*16 + lm)*HD + k0 + lq*8);
      acc[ct] = __builtin_amdgcn_mfma_f32_16x16x32_bf16(a, b, acc[ct], 0, 0, 0);
    }
  }
  int orow0 = m0 + lq*4;
  #pragma unroll
  for(int ct=0;ct<4;ct++){
    #pragma unroll
    for(int r=0;r<4;r++){
      int n = orow0 + r;
      if(n < NN) Y16[(size_t)n*HD + c0 + ct*16 + lm] = f2bf(acc[ct][r]);
    }
  }
}

// ---------- attention logits el/er per (node, head) from bf16 feat ----------
__global__ void k_elr(const u16* __restrict__ feat16, const float* __restrict__ al,
                      const float* __restrict__ ar, float* __restrict__ el,
                      float* __restrict__ er){
  int i = blockIdx.x*blockDim.x + threadIdx.x;  // n*8+h
  if(i >= NN*NH) return;
  int h = i & 7;
  const ushort4* f4 = (const ushort4*)(feat16 + (size_t)i*DH);
  const float4* a4 = (const float4*)(al + h*DH);
  const float4* b4 = (const float4*)(ar + h*DH);
  float ea=0.f, eb=0.f;
  #pragma unroll
  for(int q=0;q<8;q++){
    float4 f=bf4_to_f4(f4[q]); float4 a=a4[q], b=b4[q];
    ea += f.x*a.x + f.y*a.y + f.z*a.z + f.w*a.w;
    eb += f.x*b.x + f.y*b.y + f.z*b.z + f.w*b.w;
  }
  el[i]=ea; er[i]=eb;
}

// ---------- per-node softmax aggregation: 2 edges/iteration, 16B/lane ----------
__device__ __forceinline__ void gat_agg2(int n, int lane,
    const u16* __restrict__ feat16, const float* __restrict__ el,
    const float* __restrict__ er, const int* __restrict__ start,
    const int* __restrict__ counts, const int* __restrict__ csr_src,
    float* A){
  int half = lane >> 5;
  int l = lane & 31;
  int h = l >> 2;
  int col8 = l << 3;
  float erh = er[n*NH + h];
  int st = start[n], cnt = counts[n];
  float s = 0.f;
  #pragma unroll
  for(int j=0;j<8;j++) A[j]=0.f;
  for(int c=0; c<cnt; c+=64){
    int nrem = cnt - c;
    int lim = nrem < 64 ? nrem : 64;
    int myIdx = csr_src[st + c + (lane < lim ? lane : lim-1)];
    #pragma unroll 4
    for(int k=0; k<lim; k+=2){
      int sel = k + half;
      int sidx = __shfl(myIdx, sel, 64);
      float e = el[(size_t)sidx*NH + h] + erh;
      e = (e>0.f)? e : ALPHA*e;
      float w = (sel < lim) ? __expf(e) : 0.f;
      uint4 rv = *(const uint4*)&feat16[(size_t)sidx*HD + col8];
      float f0 = __uint_as_float(rv.x << 16);
      float f1 = __uint_as_float(rv.x & 0xffff0000u);
      float f2 = __uint_as_float(rv.y << 16);
      float f3 = __uint_as_float(rv.y & 0xffff0000u);
      float f4 = __uint_as_float(rv.z << 16);
      float f5 = __uint_as_float(rv.z & 0xffff0000u);
      float f6 = __uint_as_float(rv.w << 16);
      float f7 = __uint_as_float(rv.w & 0xffff0000u);
      s += w;
      A[0]+=w*f0; A[1]+=w*f1; A[2]+=w*f2; A[3]+=w*f3;
      A[4]+=w*f4; A[5]+=w*f5; A[6]+=w*f6; A[7]+=w*f7;
    }
  }
  s += __shfl_xor(s, 32, 64);
  #pragma unroll
  for(int j=0;j<8;j++) A[j] += __shfl_xor(A[j], 32, 64);
  float inv = 1.f/fmaxf(s, 1e-9f);
  #pragma unroll
  for(int j=0;j<8;j++) A[j] *= inv;
}

// ---------- layer 1 finalize: + b1 + x@resW1, ELU -> h1b (bf16) ----------
__global__ void k_gat1(const u16* __restrict__ feat16, const float* __restrict__ el,
    const float* __restrict__ er, const int* __restrict__ start,
    const int* __restrict__ counts, const int* __restrict__ csr_src,
    const float* __restrict__ x,
    const float* __restrict__ resW1, const float* __restrict__ b1,
    u16* __restrict__ h1b){
  int n = blockIdx.x*4 + (threadIdx.x>>6);
  int lane = threadIdx.x & 63;
  if(n>=NN) return;
  float A[8];
  gat_agg2(n,lane,feat16,el,er,start,counts,csr_src,A);
  int half = lane>>5, l = lane&31;
  int col8 = l<<3;
  float r[8];
  #pragma unroll
  for(int j=0;j<8;j++) r[j]=0.f;
  const float* xrow = x + (size_t)n*IN_F;
  int kb = half*15;
  #pragma unroll
  for(int k=0;k<15;k++){
    float xv = xrow[kb+k];
    const float4 w0 = *(const float4*)&resW1[(kb+k)*HD + col8];
    const float4 w1 = *(const float4*)&resW1[(kb+k)*HD + col8 + 4];
    r[0]+=xv*w0.x; r[1]+=xv*w0.y; r[2]+=xv*w0.z; r[3]+=xv*w0.w;
    r[4]+=xv*w1.x; r[5]+=xv*w1.y; r[6]+=xv*w1.z; r[7]+=xv*w1.w;
  }
  #pragma unroll
  for(int j=0;j<8;j++) r[j] += __shfl_xor(r[j], 32, 64);
  if(half==0){
    const float4 b0 = *(const float4*)&b1[col8];
    const float4 b4 = *(const float4*)&b1[col8+4];
    float v; ushort4 q0, q1;
    v = A[0]+r[0]+b0.x; q0.x = f2bf((v>0.f)? v : expf(v)-1.f);
    v = A[1]+r[1]+b0.y; q0.y = f2bf((v>0.f)? v : expf(v)-1.f);
    v = A[2]+r[2]+b0.z; q0.z = f2bf((v>0.f)? v : expf(v)-1.f);
    v = A[3]+r[3]+b0.w; q0.w = f2bf((v>0.f)? v : expf(v)-1.f);
    v = A[4]+r[4]+b4.x; q1.x = f2bf((v>0.f)? v : expf(v)-1.f);
    v = A[5]+r[5]+b4.y; q1.y = f2bf((v>0.f)? v : expf(v)-1.f);
    v = A[6]+r[6]+b4.z; q1.z = f2bf((v>0.f)? v : expf(v)-1.f);
    v = A[7]+r[7]+b4.w; q1.w = f2bf((v>0.f)? v : expf(v)-1.f);
    *(ushort4*)&h1b[(size_t)n*HD + col8]     = q0;
    *(ushort4*)&h1b[(size_t)n*HD + col8 + 4] = q1;
  }
}

// ---------- layer 2 finalize: + b2 + h1b residual, mean over heads -> h2 ----------
__global__ void k_gat2(const u16* __restrict__ feat16, const float* __restrict__ el,
    const float* __restrict__ er, const int* __restrict__ start,
    const int* __restrict__ counts, const int* __restrict__ csr_src,
    const u16* __restrict__ h1b,
    const float* __restrict__ b2, float* __restrict__ h2){
  int n = blockIdx.x*4 + (threadIdx.x>>6);
  int lane = threadIdx.x & 63;
  if(n>=NN) return;
  float A[8];
  gat_agg2(n,lane,feat16,el,er,start,counts,csr_src,A);
  int l = lane&31;
  int col8 = l<<3;
  if(lane<32){
    const float4 b0 = *(const float4*)&b2[col8];
    const float4 b4 = *(const float4*)&b2[col8+4];
    float4 h0 = bf4_to_f4(*(const ushort4*)&h1b[(size_t)n*HD + col8]);
    float4 h4 = bf4_to_f4(*(const ushort4*)&h1b[(size_t)n*HD + col8 + 4]);
    float t[8];
    t[0]=A[0]+b0.x+h0.x; t[1]=A[1]+b0.y+h0.y; t[2]=A[2]+b0.z+h0.z; t[3]=A[3]+b0.w+h0.w;
    t[4]=A[4]+b4.x+h4.x; t[5]=A[5]+b4.y+h4.y; t[6]=A[6]+b4.z+h4.z; t[7]=A[7]+b4.w+h4.w;
    // head-sum: lane l = h*4+p; reduce over h bits (offsets 4,8,16)
    #pragma unroll
    for(int off=4; off<32; off<<=1){
      #pragma unroll
      for(int j=0;j<8;j++) t[j] += __shfl_xor(t[j], off, 64);
    }
    if(l<4){
      float4 o0, o1;
      o0.x=t[0]*0.125f; o0.y=t[1]*0.125f; o0.z=t[2]*0.125f; o0.w=t[3]*0.125f;
      o1.x=t[4]*0.125f; o1.y=t[5]*0.125f; o1.z=t[6]*0.125f; o1.w=t[7]*0.125f;
      *(float4*)&h2[(size_t)n*DH + (l<<3)]     = o0;
      *(float4*)&h2[(size_t)n*DH + (l<<3) + 4] = o1;
    }
  }
}

// ---------- segmented readout + fused gate (NO atomics; gid is sorted) ----------
__global__ void k_readout(const float* __restrict__ h2, const float* __restrict__ Ww,
    const float* __restrict__ bw, const int* __restrict__ gstart,
    const int* __restrict__ gcounts, float* __restrict__ gsum,
    float* __restrict__ gmaxf){
  __shared__ float ssum[8][DH];
  __shared__ float smax[8][DH];
  int g = blockIdx.x;
  int t = threadIdx.x;
  int half = (t & 63) >> 5;
  int wid = t >> 6;
  int l = t & 31;
  int rg = wid*2 + half;               // row group 0..7
  int s = gstart[g], cnt = gcounts[g];
  float w_d = Ww[l];
  float bw0 = bw[0];
  float sum = 0.f, mx = -INFINITY;
  for(int r = rg; r < cnt; r += 8){
    float v = h2[(size_t)(s+r)*DH + l];
    float p = v*w_d;
    p += __shfl_xor(p,1,64); p += __shfl_xor(p,2,64); p += __shfl_xor(p,4,64);
    p += __shfl_xor(p,8,64); p += __shfl_xor(p,16,64);
    float wg = 1.f/(1.f+__expf(-(p+bw0)));
    sum += wg*v;
    mx = fmaxf(mx, v);
  }
  ssum[rg][l] = sum;
  smax[rg][l] = mx;
  __syncthreads();
  if(t < DH){
    float a = 0.f, m = -INFINITY;
    #pragma unroll
    for(int r=0;r<8;r++){ a += ssum[r][t]; m = fmaxf(m, smax[r][t]); }
    gsum[g*DH+t]  = a;
    gmaxf[g*DH+t] = isfinite(m)? m : 0.f;
  }
}

// ---------- MLP predictor: one block (128 thr) per graph ----------
__global__ void k_mlp(const float* __restrict__ gsum, const float* __restrict__ gmaxf,
    const float* __restrict__ Wp1, const float* __restrict__ bp1,
    const float* __restrict__ gamma, const float* __restrict__ beta,
    const float* __restrict__ rm, const float* __restrict__ rv,
    const float* __restrict__ Wp2, const float* __restrict__ bp2,
    float* __restrict__ out){
  __shared__ float gs[2*DH];
  __shared__ float red[NHID];
  int g = blockIdx.x, t = threadIdx.x;
  if(t < DH) gs[t] = gsum[g*DH + t];
  else if(t < 2*DH) gs[t] = gmaxf[g*DH + (t-DH)];
  __syncthreads();
  float acc = bp1[t];
  #pragma unroll
  for(int k=0;k<2*DH;k++) acc += gs[k]*Wp1[k*NHID + t];
  acc = fmaxf(acc, 0.f);
  acc = (acc - rm[t])*rsqrtf(rv[t]+1e-5f)*gamma[t] + beta[t];
  red[t] = acc*Wp2[t];
  __syncthreads();
  for(int off=NHID/2; off>0; off>>=1){
    if(t<off) red[t] += red[t+off];
    __syncthreads();
  }
  if(t==0) out[g] = red[0] + bp2[0];
}

extern "C" void kernel_launch(void* const* d_in, const int* in_sizes, int n_in,
                              void* d_out, int out_size, void* d_ws, size_t ws_size,
                              hipStream_t stream){
  const float* x    = (const float*)d_in[0];
  const int*   src  = (const int*)  d_in[1];
  const int*   dst  = (const int*)  d_in[2];
  const int*   gid  = (const int*)  d_in[3];
  const float* W1   = (const float*)d_in[4];
  const float* al1  = (const float*)d_in[5];
  const float* ar1  = (const float*)d_in[6];
  const float* b1   = (const float*)d_in[7];
  const float* resW1= (const float*)d_in[8];
  const float* W2   = (const float*)d_in[9];
  const float* al2  = (const float*)d_in[10];
  const float* ar2  = (const float*)d_in[11];
  const float* b2   = (const float*)d_in[12];
  const float* Ww   = (const float*)d_in[13];
  const float* bw   = (const float*)d_in[14];
  const float* Wp1  = (const float*)d_in[15];
  const float* bp1  = (const float*)d_in[16];
  const float* gamma= (const float*)d_in[17];
  const float* beta = (const float*)d_in[18];
  const float* rm   = (const float*)d_in[19];
  const float* rv   = (const float*)d_in[20];
  const float* Wp2  = (const float*)d_in[21];
  const float* bp2  = (const float*)d_in[22];
  float* out = (float*)d_out;

  char* w = (char*)d_ws;
  u16*      feat16 = (u16*)w;      w += (size_t)NN*HD*2;
  u16*      h1b    = (u16*)w;      w += (size_t)NN*HD*2;
  u16*      W2T    = (u16*)w;      w += (size_t)HD*HD*2;
  float*    el     = (float*)w;    w += (size_t)NN*NH*4;
  float*    er     = (float*)w;    w += (size_t)NN*NH*4;
  float*    h2     = (float*)w;    w += (size_t)NN*DH*4;
  float*    gsum   = (float*)w;    w += (size_t)NG*DH*4;
  float*    gmaxf  = (float*)w;    w += (size_t)NG*DH*4;
  int*      counts = (int*)w;      w += (size_t)NN*4;
  int*      start  = (int*)w;      w += (size_t)NN*4;
  int*      cursor = (int*)w;      w += (size_t)NN*4;
  int*      bsums  = (int*)w;      w += (size_t)SCAN_NB*4;
  int*      gcounts= (int*)w;      w += (size_t)NG*4;
  int*      gstart = (int*)w;      w += (size_t)NG*4;
  int*      csr_src= (int*)w;      w += (size_t)EE*4;

  hipLaunchKernelGGL(k_init,         dim3((NN+255)/256),       dim3(256),    0, stream, counts, gcounts);
  hipLaunchKernelGGL(k_hist,         dim3((EE+255)/256),       dim3(256),    0, stream, dst, counts);
  hipLaunchKernelGGL(k_ghist,        dim3((NN+255)/256),       dim3(256),    0, stream, gid, gcounts);
  hipLaunchKernelGGL(k_gscan,        dim3(1),                  dim3(NG),     0, stream, gcounts, gstart);
  hipLaunchKernelGGL(k_scan_partial, dim3(SCAN_NB),            dim3(SCAN_B), 0, stream, counts, bsums);
  hipLaunchKernelGGL(k_scan_bsums,   dim3(1),                  dim3(SCAN_B), 0, stream, bsums);
  hipLaunchKernelGGL(k_scan_final,   dim3(SCAN_NB),            dim3(SCAN_B), 0, stream, counts, bsums, start, cursor);
  hipLaunchKernelGGL(k_scatter,      dim3((EE+255)/256),       dim3(256),    0, stream, dst, src, cursor, csr_src);
  hipLaunchKernelGGL(k_w2t,          dim3((HD*HD+255)/256),    dim3(256),    0, stream, W2, W2T);
  hipLaunchKernelGGL(k_proj1,        dim3(NN/TM1),             dim3(256),    0, stream, x, W1, feat16);
  hipLaunchKernelGGL(k_elr,          dim3((NN*NH+255)/256),    dim3(256),    0, stream, feat16, al1, ar1, el, er);
  hipLaunchKernelGGL(k_gat1,         dim3((NN+3)/4),           dim3(256),    0, stream, feat16, el, er, start, counts, csr_src, x, resW1, b1, h1b);
  hipLaunchKernelGGL(k_proj2m,       dim3((NN+63)/64, HD/64),  dim3(256),    0, stream, h1b, W2T, feat16);
  hipLaunchKernelGGL(k_elr,          dim3((NN*NH+255)/256),    dim3(256),    0, stream, feat16, al2, ar2, el, er);
  hipLaunchKernelGGL(k_gat2,         dim3((NN+3)/4),           dim3(256),    0, stream, feat16, el, er, start, counts, csr_src, h1b, b2, h2);
  hipLaunchKernelGGL(k_readout,      dim3(NG),                 dim3(256),    0, stream, h2, Ww, bw, gstart, gcounts, gsum, gmaxf);
  hipLaunchKernelGGL(k_mlp,          dim3(NG),                 dim3(NHID),   0, stream, gsum, gmaxf, Wp1, bp1, gamma, beta, rm, rv, Wp2, bp2, out);
}

// Round 16
// 519.494 us; speedup vs baseline: 1.4398x; 1.0219x over previous
//
#include <hip/hip_runtime.h>
#include <math.h>

#define NN 50000
#define EE 800000
#define IN_F 30
#define NH 8
#define DH 32
#define HD 256      // NH*DH
#define NG 512
#define NHID 128
#define ALPHA 0.2f

#define SCAN_B 256
#define SCAN_NB ((NN + SCAN_B - 1)/SCAN_B)   // 196
#define P1B (NN/16)                           // proj1 blocks (3125)

typedef unsigned short u16;
typedef __attribute__((ext_vector_type(8))) short bf16x8;
typedef __attribute__((ext_vector_type(4))) float f32x4;

// ---------- bf16 helpers (round-to-nearest-even) ----------
__device__ __forceinline__ u16 f2bf(float f){
  unsigned u = __float_as_uint(f);
  u = u + 0x7FFFu + ((u >> 16) & 1u);
  return (u16)(u >> 16);
}
__device__ __forceinline__ float bf2f(u16 b){
  return __uint_as_float(((unsigned)b) << 16);
}
__device__ __forceinline__ float4 bf4_to_f4(ushort4 v){
  float4 r; r.x=bf2f(v.x); r.y=bf2f(v.y); r.z=bf2f(v.z); r.w=bf2f(v.w); return r;
}

// ---------- init: zero counts + graph counts ----------
__global__ void k_init(int* counts, int* gcounts){
  int i = blockIdx.x*blockDim.x + threadIdx.x;
  if(i < NN) counts[i] = 0;
  if(i < NG) gcounts[i] = 0;
}

// ---------- FUSED histograms: CSR by dst + graph segments ----------
__global__ void k_hist2(const int* __restrict__ dst, const int* __restrict__ gid,
                        int* counts, int* gcounts){
  int i = blockIdx.x*blockDim.x + threadIdx.x;
  if(i < EE) atomicAdd(&counts[dst[i]], 1);
  if(i < NN) atomicAdd(&gcounts[gid[i]], 1);
}

// ---------- hierarchical scan phase 1 (block sums) ----------
__global__ void k_scan_partial(const int* __restrict__ counts, int* __restrict__ bsums){
  __shared__ int sd[SCAN_B];
  int b = blockIdx.x, t = threadIdx.x;
  int idx = b*SCAN_B + t;
  sd[t] = (idx<NN)? counts[idx] : 0;
  __syncthreads();
  for(int off=SCAN_B/2; off>0; off>>=1){
    if(t<off) sd[t] += sd[t+off];
    __syncthreads();
  }
  if(t==0) bsums[b] = sd[0];
}

// ---------- FUSED small scans: block 0 = graph starts, block 1 = bsums ----------
__global__ void k_scan2(const int* __restrict__ gcounts, int* __restrict__ gstart,
                        int* __restrict__ bsums){
  __shared__ int sd[NG];
  int t = threadIdx.x;                 // 0..511
  if(blockIdx.x == 0){
    int v = gcounts[t];
    sd[t]=v; __syncthreads();
    for(int off=1; off<NG; off<<=1){
      int u = (t>=off)? sd[t-off] : 0;
      __syncthreads();
      sd[t] += u;
      __syncthreads();
    }
    gstart[t] = sd[t]-v;               // exclusive
  } else {
    int v = (t<SCAN_NB)? bsums[t] : 0;
    sd[t]=v; __syncthreads();
    for(int off=1; off<NG; off<<=1){
      int u = (t>=off)? sd[t-off] : 0;
      __syncthreads();
      sd[t] += u;
      __syncthreads();
    }
    if(t<SCAN_NB) bsums[t] = sd[t]-v;  // exclusive
  }
}

// ---------- scan phase 3: block-local scan + offset -> start, cursor ----------
__global__ void k_scan_final(const int* __restrict__ counts, const int* __restrict__ bsums,
                             int* __restrict__ start, int* __restrict__ cursor){
  __shared__ int sd[SCAN_B];
  int b = blockIdx.x, t = threadIdx.x;
  int idx = b*SCAN_B + t;
  int v = (idx<NN)? counts[idx] : 0;
  sd[t]=v; __syncthreads();
  for(int off=1; off<SCAN_B; off<<=1){
    int u = (t>=off)? sd[t-off] : 0;
    __syncthreads();
    sd[t] += u;
    __syncthreads();
  }
  int ex = sd[t]-v + bsums[b];
  if(idx<NN){ start[idx]=ex; cursor[idx]=ex; }
}

// ---------- scatter SOURCE NODE IDS into dst-grouped order ----------
__global__ void k_scatter(const int* __restrict__ dst, const int* __restrict__ src,
                          int* cursor, int* __restrict__ csr_src){
  int i = blockIdx.x*blockDim.x + threadIdx.x;
  if(i<EE){ int p = atomicAdd(&cursor[dst[i]],1); csr_src[p]=src[i]; }
}

// ---------- layer-1 projection (blocks < P1B) + W2 transpose tail ----------
#define TM1 16
__global__ void k_proj1w(const float* __restrict__ x, const float* __restrict__ W1,
                         u16* __restrict__ feat16, const float* __restrict__ W2,
                         u16* __restrict__ W2T){
  if(blockIdx.x >= P1B){                       // W2T tail: 256 blocks
    int i = (blockIdx.x - P1B)*256 + threadIdx.x;   // < HD*HD
    int n = i >> 8, k = i & 255;
    W2T[i] = f2bf(W2[k*HD + n]);
    return;                                    // block-uniform exit (no barrier crossed)
  }
  __shared__ float xs[TM1][IN_F];
  int n0 = blockIdx.x*TM1;
  int t = threadIdx.x;
  for(int i=t;i<TM1*IN_F;i+=256){
    int m=i/IN_F, k=i-m*IN_F;
    xs[m][k] = x[(size_t)(n0+m)*IN_F+k];
  }
  __syncthreads();
  int jq = (t & 63) << 2;
  int m0 = t >> 6;
  float4 acc[4];
  #pragma unroll
  for(int r=0;r<4;r++){ acc[r].x=0.f; acc[r].y=0.f; acc[r].z=0.f; acc[r].w=0.f; }
  for(int k=0;k<IN_F;k++){
    float4 w = *(const float4*)&W1[k*HD + jq];
    #pragma unroll
    for(int r=0;r<4;r++){
      float xv = xs[m0 + (r<<2)][k];
      acc[r].x += xv*w.x; acc[r].y += xv*w.y; acc[r].z += xv*w.z; acc[r].w += xv*w.w;
    }
  }
  #pragma unroll
  for(int r=0;r<4;r++){
    int n = n0 + m0 + (r<<2);
    ushort4 o; o.x=f2bf(acc[r].x); o.y=f2bf(acc[r].y); o.z=f2bf(acc[r].z); o.w=f2bf(acc[r].w);
    *(ushort4*)&feat16[(size_t)n*HD + jq] = o;
  }
}

// ---------- layer-2 projection via MFMA: feat2 = bf16(h1b @ W2) ----------
// A frag: A[m=lane&15][k=quad*8+j]; B frag from W2T: B[n=lane&15][k];
// C/D: col=lane&15, row=quad*4+reg (verified layouts).
__global__ void k_proj2m(const u16* __restrict__ h1b, const u16* __restrict__ W2T,
                         u16* __restrict__ Y16){
  int t = threadIdx.x;
  int wave = t>>6, lane = t&63;
  int m0 = blockIdx.x*64 + wave*16;
  int c0 = blockIdx.y*64;
  int lm = lane & 15, lq = lane >> 4;
  int arow = m0 + lm; if(arow >= NN) arow = NN-1;   // clamp (stores guarded)
  const u16* Aptr = h1b + (size_t)arow*HD + lq*8;
  f32x4 acc[4];
  #pragma unroll
  for(int ct=0;ct<4;ct++) acc[ct] = (f32x4){0.f,0.f,0.f,0.f};
  #pragma unroll
  for(int k0=0;k0<HD;k0+=32){
    bf16x8 a = *(const bf16x8*)(Aptr + k0);
    #pragma unroll
    for(int ct=0;ct<4;ct++){
      bf16x8 b = *(const bf16x8*)(W2T + (size_t)(c0 + ct*16 + lm)*HD + k0 + lq*8);
      acc[ct] = __builtin_amdgcn_mfma_f32_16x16x32_bf16(a, b, acc[ct], 0, 0, 0);
    }
  }
  int orow0 = m0 + lq*4;
  #pragma unroll
  for(int ct=0;ct<4;ct++){
    #pragma unroll
    for(int r=0;r<4;r++){
      int n = orow0 + r;
      if(n < NN) Y16[(size_t)n*HD + c0 + ct*16 + lm] = f2bf(acc[ct][r]);
    }
  }
}

// ---------- attention logits el/er per (node, head) from bf16 feat ----------
__global__ void k_elr(const u16* __restrict__ feat16, const float* __restrict__ al,
                      const float* __restrict__ ar, float* __restrict__ el,
                      float* __restrict__ er){
  int i = blockIdx.x*blockDim.x + threadIdx.x;  // n*8+h
  if(i >= NN*NH) return;
  int h = i & 7;
  const ushort4* f4 = (const ushort4*)(feat16 + (size_t)i*DH);
  const float4* a4 = (const float4*)(al + h*DH);
  const float4* b4 = (const float4*)(ar + h*DH);
  float ea=0.f, eb=0.f;
  #pragma unroll
  for(int q=0;q<8;q++){
    float4 f=bf4_to_f4(f4[q]); float4 a=a4[q], b=b4[q];
    ea += f.x*a.x + f.y*a.y + f.z*a.z + f.w*a.w;
    eb += f.x*b.x + f.y*b.y + f.z*b.z + f.w*b.w;
  }
  el[i]=ea; er[i]=eb;
}

// ---------- per-node softmax aggregation: 2 edges/iteration, 16B/lane ----------
__device__ __forceinline__ void gat_agg2(int n, int lane,
    const u16* __restrict__ feat16, const float* __restrict__ el,
    const float* __restrict__ er, const int* __restrict__ start,
    const int* __restrict__ counts, const int* __restrict__ csr_src,
    float* A){
  int half = lane >> 5;
  int l = lane & 31;
  int h = l >> 2;
  int col8 = l << 3;
  float erh = er[n*NH + h];
  int st = start[n], cnt = counts[n];
  float s = 0.f;
  #pragma unroll
  for(int j=0;j<8;j++) A[j]=0.f;
  for(int c=0; c<cnt; c+=64){
    int nrem = cnt - c;
    int lim = nrem < 64 ? nrem : 64;
    int myIdx = csr_src[st + c + (lane < lim ? lane : lim-1)];
    #pragma unroll 4
    for(int k=0; k<lim; k+=2){
      int sel = k + half;
      int sidx = __shfl(myIdx, sel, 64);
      float e = el[(size_t)sidx*NH + h] + erh;
      e = (e>0.f)? e : ALPHA*e;
      float w = (sel < lim) ? __expf(e) : 0.f;
      uint4 rv = *(const uint4*)&feat16[(size_t)sidx*HD + col8];
      float f0 = __uint_as_float(rv.x << 16);
      float f1 = __uint_as_float(rv.x & 0xffff0000u);
      float f2 = __uint_as_float(rv.y << 16);
      float f3 = __uint_as_float(rv.y & 0xffff0000u);
      float f4 = __uint_as_float(rv.z << 16);
      float f5 = __uint_as_float(rv.z & 0xffff0000u);
      float f6 = __uint_as_float(rv.w << 16);
      float f7 = __uint_as_float(rv.w & 0xffff0000u);
      s += w;
      A[0]+=w*f0; A[1]+=w*f1; A[2]+=w*f2; A[3]+=w*f3;
      A[4]+=w*f4; A[5]+=w*f5; A[6]+=w*f6; A[7]+=w*f7;
    }
  }
  s += __shfl_xor(s, 32, 64);
  #pragma unroll
  for(int j=0;j<8;j++) A[j] += __shfl_xor(A[j], 32, 64);
  float inv = 1.f/fmaxf(s, 1e-9f);
  #pragma unroll
  for(int j=0;j<8;j++) A[j] *= inv;
}

// ---------- layer 1 finalize: + b1 + x@resW1, ELU -> h1b (bf16) ----------
__global__ void k_gat1(const u16* __restrict__ feat16, const float* __restrict__ el,
    const float* __restrict__ er, const int* __restrict__ start,
    const int* __restrict__ counts, const int* __restrict__ csr_src,
    const float* __restrict__ x,
    const float* __restrict__ resW1, const float* __restrict__ b1,
    u16* __restrict__ h1b){
  int n = blockIdx.x*4 + (threadIdx.x>>6);
  int lane = threadIdx.x & 63;
  if(n>=NN) return;
  float A[8];
  gat_agg2(n,lane,feat16,el,er,start,counts,csr_src,A);
  int half = lane>>5, l = lane&31;
  int col8 = l<<3;
  float r[8];
  #pragma unroll
  for(int j=0;j<8;j++) r[j]=0.f;
  const float* xrow = x + (size_t)n*IN_F;
  int kb = half*15;
  #pragma unroll
  for(int k=0;k<15;k++){
    float xv = xrow[kb+k];
    const float4 w0 = *(const float4*)&resW1[(kb+k)*HD + col8];
    const float4 w1 = *(const float4*)&resW1[(kb+k)*HD + col8 + 4];
    r[0]+=xv*w0.x; r[1]+=xv*w0.y; r[2]+=xv*w0.z; r[3]+=xv*w0.w;
    r[4]+=xv*w1.x; r[5]+=xv*w1.y; r[6]+=xv*w1.z; r[7]+=xv*w1.w;
  }
  #pragma unroll
  for(int j=0;j<8;j++) r[j] += __shfl_xor(r[j], 32, 64);
  if(half==0){
    const float4 b0 = *(const float4*)&b1[col8];
    const float4 b4 = *(const float4*)&b1[col8+4];
    float v; ushort4 q0, q1;
    v = A[0]+r[0]+b0.x; q0.x = f2bf((v>0.f)? v : expf(v)-1.f);
    v = A[1]+r[1]+b0.y; q0.y = f2bf((v>0.f)? v : expf(v)-1.f);
    v = A[2]+r[2]+b0.z; q0.z = f2bf((v>0.f)? v : expf(v)-1.f);
    v = A[3]+r[3]+b0.w; q0.w = f2bf((v>0.f)? v : expf(v)-1.f);
    v = A[4]+r[4]+b4.x; q1.x = f2bf((v>0.f)? v : expf(v)-1.f);
    v = A[5]+r[5]+b4.y; q1.y = f2bf((v>0.f)? v : expf(v)-1.f);
    v = A[6]+r[6]+b4.z; q1.z = f2bf((v>0.f)? v : expf(v)-1.f);
    v = A[7]+r[7]+b4.w; q1.w = f2bf((v>0.f)? v : expf(v)-1.f);
    *(ushort4*)&h1b[(size_t)n*HD + col8]     = q0;
    *(ushort4*)&h1b[(size_t)n*HD + col8 + 4] = q1;
  }
}

// ---------- layer 2 finalize: + b2 + h1b residual, mean over heads -> h2 ----------
__global__ void k_gat2(const u16* __restrict__ feat16, const float* __restrict__ el,
    const float* __restrict__ er, const int* __restrict__ start,
    const int* __restrict__ counts, const int* __restrict__ csr_src,
    const u16* __restrict__ h1b,
    const float* __restrict__ b2, float* __restrict__ h2){
  int n = blockIdx.x*4 + (threadIdx.x>>6);
  int lane = threadIdx.x & 63;
  if(n>=NN) return;
  float A[8];
  gat_agg2(n,lane,feat16,el,er,start,counts,csr_src,A);
  int l = lane&31;
  int col8 = l<<3;
  if(lane<32){
    const float4 b0 = *(const float4*)&b2[col8];
    const float4 b4 = *(const float4*)&b2[col8+4];
    float4 h0 = bf4_to_f4(*(const ushort4*)&h1b[(size_t)n*HD + col8]);
    float4 h4 = bf4_to_f4(*(const ushort4*)&h1b[(size_t)n*HD + col8 + 4]);
    float t[8];
    t[0]=A[0]+b0.x+h0.x; t[1]=A[1]+b0.y+h0.y; t[2]=A[2]+b0.z+h0.z; t[3]=A[3]+b0.w+h0.w;
    t[4]=A[4]+b4.x+h4.x; t[5]=A[5]+b4.y+h4.y; t[6]=A[6]+b4.z+h4.z; t[7]=A[7]+b4.w+h4.w;
    // head-sum: lane l = h*4+p; reduce over h bits (offsets 4,8,16)
    #pragma unroll
    for(int off=4; off<32; off<<=1){
      #pragma unroll
      for(int j=0;j<8;j++) t[j] += __shfl_xor(t[j], off, 64);
    }
    if(l<4){
      float4 o0, o1;
      o0.x=t[0]*0.125f; o0.y=t[1]*0.125f; o0.z=t[2]*0.125f; o0.w=t[3]*0.125f;
      o1.x=t[4]*0.125f; o1.y=t[5]*0.125f; o1.z=t[6]*0.125f; o1.w=t[7]*0.125f;
      *(float4*)&h2[(size_t)n*DH + (l<<3)]     = o0;
      *(float4*)&h2[(size_t)n*DH + (l<<3) + 4] = o1;
    }
  }
}

// ---------- segmented readout + fused gate + FUSED MLP (one block per graph) ----------
__global__ void k_readout(const float* __restrict__ h2, const float* __restrict__ Ww,
    const float* __restrict__ bw, const int* __restrict__ gstart,
    const int* __restrict__ gcounts,
    const float* __restrict__ Wp1, const float* __restrict__ bp1,
    const float* __restrict__ gamma, const float* __restrict__ beta,
    const float* __restrict__ rm, const float* __restrict__ rv,
    const float* __restrict__ Wp2, const float* __restrict__ bp2,
    float* __restrict__ out){
  __shared__ float ssum[8][DH];
  __shared__ float smax[8][DH];
  __shared__ float gs[2*DH];
  __shared__ float red[NHID];
  int g = blockIdx.x;
  int t = threadIdx.x;
  int half = (t & 63) >> 5;
  int wid = t >> 6;
  int l = t & 31;
  int rg = wid*2 + half;               // row group 0..7
  int s = gstart[g], cnt = gcounts[g];
  float w_d = Ww[l];
  float bw0 = bw[0];
  float sum = 0.f, mx = -INFINITY;
  for(int r = rg; r < cnt; r += 8){
    float v = h2[(size_t)(s+r)*DH + l];
    float p = v*w_d;
    p += __shfl_xor(p,1,64); p += __shfl_xor(p,2,64); p += __shfl_xor(p,4,64);
    p += __shfl_xor(p,8,64); p += __shfl_xor(p,16,64);
    float wg = 1.f/(1.f+__expf(-(p+bw0)));
    sum += wg*v;
    mx = fmaxf(mx, v);
  }
  ssum[rg][l] = sum;
  smax[rg][l] = mx;
  __syncthreads();
  if(t < DH){
    float a = 0.f, m = -INFINITY;
    #pragma unroll
    for(int r=0;r<8;r++){ a += ssum[r][t]; m = fmaxf(m, smax[r][t]); }
    gs[t]      = a;
    gs[DH + t] = isfinite(m)? m : 0.f;   // empty-segment guard
  }
  __syncthreads();
  // MLP: hidden unit t (t < 128)
  if(t < NHID){
    float acc = bp1[t];
    #pragma unroll
    for(int k=0;k<2*DH;k++) acc += gs[k]*Wp1[k*NHID + t];
    acc = fmaxf(acc, 0.f);
    acc = (acc - rm[t])*rsqrtf(rv[t]+1e-5f)*gamma[t] + beta[t];
    red[t] = acc*Wp2[t];
  }
  __syncthreads();
  for(int off=NHID/2; off>0; off>>=1){
    if(t<off) red[t] += red[t+off];
    __syncthreads();
  }
  if(t==0) out[g] = red[0] + bp2[0];
}

extern "C" void kernel_launch(void* const* d_in, const int* in_sizes, int n_in,
                              void* d_out, int out_size, void* d_ws, size_t ws_size,
                              hipStream_t stream){
  const float* x    = (const float*)d_in[0];
  const int*   src  = (const int*)  d_in[1];
  const int*   dst  = (const int*)  d_in[2];
  const int*   gid  = (const int*)  d_in[3];
  const float* W1   = (const float*)d_in[4];
  const float* al1  = (const float*)d_in[5];
  const float* ar1  = (const float*)d_in[6];
  const float* b1   = (const float*)d_in[7];
  const float* resW1= (const float*)d_in[8];
  const float* W2   = (const float*)d_in[9];
  const float* al2  = (const float*)d_in[10];
  const float* ar2  = (const float*)d_in[11];
  const float* b2   = (const float*)d_in[12];
  const float* Ww   = (const float*)d_in[13];
  const float* bw   = (const float*)d_in[14];
  const float* Wp1  = (const float*)d_in[15];
  const float* bp1  = (const float*)d_in[16];
  const float* gamma= (const float*)d_in[17];
  const float* beta = (const float*)d_in[18];
  const float* rm   = (const float*)d_in[19];
  const float* rv   = (const float*)d_in[20];
  const float* Wp2  = (const float*)d_in[21];
  const float* bp2  = (const float*)d_in[22];
  float* out = (float*)d_out;

  char* w = (char*)d_ws;
  u16*      feat16 = (u16*)w;      w += (size_t)NN*HD*2;
  u16*      h1b    = (u16*)w;      w += (size_t)NN*HD*2;
  u16*      W2T    = (u16*)w;      w += (size_t)HD*HD*2;
  float*    el     = (float*)w;    w += (size_t)NN*NH*4;
  float*    er     = (float*)w;    w += (size_t)NN*NH*4;
  float*    h2     = (float*)w;    w += (size_t)NN*DH*4;
  int*      counts = (int*)w;      w += (size_t)NN*4;
  int*      start  = (int*)w;      w += (size_t)NN*4;
  int*      cursor = (int*)w;      w += (size_t)NN*4;
  int*      bsums  = (int*)w;      w += (size_t)SCAN_NB*4;
  int*      gcounts= (int*)w;      w += (size_t)NG*4;
  int*      gstart = (int*)w;      w += (size_t)NG*4;
  int*      csr_src= (int*)w;      w += (size_t)EE*4;

  hipLaunchKernelGGL(k_init,         dim3((NN+255)/256),        dim3(256),    0, stream, counts, gcounts);
  hipLaunchKernelGGL(k_hist2,        dim3((EE+255)/256),        dim3(256),    0, stream, dst, gid, counts, gcounts);
  hipLaunchKernelGGL(k_scan_partial, dim3(SCAN_NB),             dim3(SCAN_B), 0, stream, counts, bsums);
  hipLaunchKernelGGL(k_scan2,        dim3(2),                   dim3(NG),     0, stream, gcounts, gstart, bsums);
  hipLaunchKernelGGL(k_scan_final,   dim3(SCAN_NB),             dim3(SCAN_B), 0, stream, counts, bsums, start, cursor);
  hipLaunchKernelGGL(k_scatter,      dim3((EE+255)/256),        dim3(256),    0, stream, dst, src, cursor, csr_src);
  hipLaunchKernelGGL(k_proj1w,       dim3(P1B + HD*HD/256),     dim3(256),    0, stream, x, W1, feat16, W2, W2T);
  hipLaunchKernelGGL(k_elr,          dim3((NN*NH+255)/256),     dim3(256),    0, stream, feat16, al1, ar1, el, er);
  hipLaunchKernelGGL(k_gat1,         dim3((NN+3)/4),            dim3(256),    0, stream, feat16, el, er, start, counts, csr_src, x, resW1, b1, h1b);
  hipLaunchKernelGGL(k_proj2m,       dim3((NN+63)/64, HD/64),   dim3(256),    0, stream, h1b, W2T, feat16);
  hipLaunchKernelGGL(k_elr,          dim3((NN*NH+255)/256),     dim3(256),    0, stream, feat16, al2, ar2, el, er);
  hipLaunchKernelGGL(k_gat2,         dim3((NN+3)/4),            dim3(256),    0, stream, feat16, el, er, start, counts, csr_src, h1b, b2, h2);
  hipLaunchKernelGGL(k_readout,      dim3(NG),                  dim3(256),    0, stream, h2, Ww, bw, gstart, gcounts, Wp1, bp1, gamma, beta, rm, rv, Wp2, bp2, out);
}